// Round 5
// baseline (554.947 us; speedup 1.0000x reference)
//
#include <hip/hip_runtime.h>
#include <hip/hip_bf16.h>
#include <math.h>
#include <stdint.h>

#define B_BATCH   1024
#define D_DIM     512
#define C_CLASSES 100000
#define BM        128
#define BN        128
#define BK        32
#define KITERS    (D_DIM / BK)                    // 16
#define MTILES    (B_BATCH / BM)                  // 8
#define NTILES    ((C_CLASSES + BN - 1) / BN)     // 782
#define NGROUPS   98                              // ceil(782/8)
#define GRID_G    (8 * 8 * NGROUPS)               // 6272 blocks (16 early-exit)
#define LOG2E     1.44269504088896340736f
#define COSM      0.87758256189037276f            // cos(0.5)
#define SINM      0.47942553860420301f            // sin(0.5)
#define NEG_LOG_EPS 69.07755278982137f            // -ln(1e-30)

typedef short bf16x8 __attribute__((ext_vector_type(8)));
typedef float f32x4  __attribute__((ext_vector_type(4)));

static __device__ __forceinline__ unsigned short f2bf(float f) {
    unsigned int u = __builtin_bit_cast(unsigned int, f);
    u += 0x7fffu + ((u >> 16) & 1u);              // round-to-nearest-even
    return (unsigned short)(u >> 16);
}

// async 16B/lane global -> LDS (LDS dest = wave-uniform base + lane*16)
static __device__ __forceinline__ void gld16(const unsigned short* g, unsigned short* l) {
    __builtin_amdgcn_global_load_lds(
        (const __attribute__((address_space(1))) unsigned int*)g,
        (__attribute__((address_space(3))) unsigned int*)l, 16, 0, 0);
}

// ---------------- kernel 1: normalize embeddings -> bf16 A [1024 x 512] ---
__global__ __launch_bounds__(256) void norm_embed(const float* __restrict__ E,
                                                  unsigned short* __restrict__ Abf) {
    const int b = blockIdx.x;
    const int t = threadIdx.x;
    float2 v = ((const float2*)(E + (size_t)b * D_DIM))[t];
    float ss = v.x * v.x + v.y * v.y;
    #pragma unroll
    for (int off = 1; off < 64; off <<= 1) ss += __shfl_xor(ss, off);
    __shared__ float ws4[4];
    if ((t & 63) == 0) ws4[t >> 6] = ss;
    __syncthreads();
    float inv = rsqrtf(ws4[0] + ws4[1] + ws4[2] + ws4[3]);
    unsigned int packed = (unsigned int)f2bf(v.x * inv) |
                          ((unsigned int)f2bf(v.y * inv) << 16);
    ((unsigned int*)Abf)[(size_t)b * (D_DIM / 2) + t] = packed;
}

// ---------------- kernel 1b: normalize weights -> bf16 [C x 512] ----------
__global__ __launch_bounds__(256) void norm_weight(const float* __restrict__ W,
                                                   unsigned short* __restrict__ Wbf) {
    const int wave = threadIdx.x >> 6;
    const int lane = threadIdx.x & 63;
    const int row = blockIdx.x * 4 + wave;
    if (row >= C_CLASSES) return;
    const float4* src = (const float4*)(W + (size_t)row * D_DIM);
    float4 v0 = src[lane];
    float4 v1 = src[lane + 64];
    float ss = v0.x*v0.x + v0.y*v0.y + v0.z*v0.z + v0.w*v0.w
             + v1.x*v1.x + v1.y*v1.y + v1.z*v1.z + v1.w*v1.w;
    #pragma unroll
    for (int off = 1; off < 64; off <<= 1) ss += __shfl_xor(ss, off);
    float inv = rsqrtf(ss);
    ushort4 o0, o1;
    o0.x = f2bf(v0.x*inv); o0.y = f2bf(v0.y*inv); o0.z = f2bf(v0.z*inv); o0.w = f2bf(v0.w*inv);
    o1.x = f2bf(v1.x*inv); o1.y = f2bf(v1.y*inv); o1.z = f2bf(v1.z*inv); o1.w = f2bf(v1.w*inv);
    ushort4* dst = (ushort4*)(Wbf + (size_t)row * D_DIM);
    dst[lane] = o0;
    dst[lane + 64] = o1;
}

// epilogue per-element: clip, ArcFace margin (identity form, no libm),
// returns exp(s - 64)
static __device__ __forceinline__ float epi_term(float accv, int col, int lab,
                                                 float* __restrict__ st, int srow) {
    float c = fminf(1.f, fmaxf(-1.f, accv));
    if (col >= C_CLASSES) return 0.f;
    float s = c * 64.0f;
    if (col == lab) {
        float sn = sqrtf(fmaxf(0.f, 1.f - c * c));
        float nm = c * COSM - sn * SINM;          // cos(theta + m)
        if (c < -COSM) nm = -1.f;                 // theta + m > pi
        s = nm * 64.0f;
        st[srow] = s;                             // unique writer across grid
    }
    return exp2f((s - 64.0f) * LOG2E);
}

// ---------------- kernel 2: bf16 GEMM + margin + partial softmax ----------
// 1D grid, XCD-colocating decode: hardware XCD = blockIdx % 8 (round-robin
// heuristic). We map the 8 m-tiles sharing W n-tile y onto 8 CONSECUTIVE
// slots of ONE XCD -> the 128x512 bf16 W-tile is fetched once into that
// XCD's L2 and reused 8x. A (1 MB) is L2-resident everywhere.
// K-loop: double-buffered LDS, ONE barrier per iter; loads for tile k+1 are
// issued right after the barrier and have the whole tile-k compute phase to
// complete before the next barrier's vmcnt(0) drain.
__global__ __launch_bounds__(256) void gemm_cos(const unsigned short* __restrict__ Abf,
                                                const unsigned short* __restrict__ Wbf,
                                                const int* __restrict__ labels,
                                                float* __restrict__ st,
                                                float* __restrict__ partial) {
    __shared__ unsigned short As[2][BM * BK];   // 2 x 8 KiB
    __shared__ unsigned short Bs[2][BN * BK];   // 2 x 8 KiB
    __shared__ float rowSum[BM];
    __shared__ int   labs[BM];

    const int id = blockIdx.x;
    const int x  = id & 7;          // XCD slot
    const int s  = id >> 3;         // sequence on this XCD: 0..783
    const int mt = s & 7;           // m-tile
    const int y  = x + 8 * (s >> 3);// n-tile: consecutive s share y per XCD
    if (y >= NTILES) return;
    const int m0 = mt * BM;
    const int n0 = y * BN;

    const int tid = threadIdx.x;
    if (tid < BM) { labs[tid] = labels[m0 + tid]; rowSum[tid] = 0.f; }

    const int lane = tid & 63;
    const int wave = tid >> 6;
    const int wm = wave & 1, wn = wave >> 1;
    const int l15 = lane & 15, quad = lane >> 4;

    // staging: wave w stages chunks (2w),(2w+1); chunk c = tile rows [16c,16c+16)
    const int rsub = lane >> 2;
    const int cg   = (lane & 3) * 8;
    const int c0 = wave * 2, c1 = wave * 2 + 1;
    const unsigned short* gA0 = Abf + (size_t)(m0 + c0 * 16 + rsub) * D_DIM + cg;
    const unsigned short* gA1 = Abf + (size_t)(m0 + c1 * 16 + rsub) * D_DIM + cg;
    const int bR0 = min(n0 + c0 * 16 + rsub, C_CLASSES - 1);
    const int bR1 = min(n0 + c1 * 16 + rsub, C_CLASSES - 1);
    const unsigned short* gB0 = Wbf + (size_t)bR0 * D_DIM + cg;
    const unsigned short* gB1 = Wbf + (size_t)bR1 * D_DIM + cg;
    const int lo0 = c0 * 512, lo1 = c1 * 512;   // LDS chunk offsets (elements)

    const f32x4 z = (f32x4){0.f, 0.f, 0.f, 0.f};
    f32x4 a00 = z, a01 = z, a02 = z, a03 = z;
    f32x4 a10 = z, a11 = z, a12 = z, a13 = z;
    f32x4 a20 = z, a21 = z, a22 = z, a23 = z;
    f32x4 a30 = z, a31 = z, a32 = z, a33 = z;

    // loop-invariant fragment offsets
    const int aro = (wm * 64 + l15) * BK + quad * 8;
    const int bro = (wn * 64 + l15) * BK + quad * 8;

    // prologue: stage tile 0 into buffer 0
    gld16(gA0, &As[0][lo0]); gld16(gA1, &As[0][lo1]);
    gld16(gB0, &Bs[0][lo0]); gld16(gB1, &Bs[0][lo1]);
    gA0 += BK; gA1 += BK; gB0 += BK; gB1 += BK;

    #pragma unroll
    for (int kk = 0; kk < KITERS; ++kk) {
        const int cur = kk & 1, nxt = cur ^ 1;
        __syncthreads();                 // tile kk arrived; prior frag reads done
        if (kk + 1 < KITERS) {           // issue tile kk+1 (drains at NEXT barrier)
            gld16(gA0, &As[nxt][lo0]); gld16(gA1, &As[nxt][lo1]);
            gld16(gB0, &Bs[nxt][lo0]); gld16(gB1, &Bs[nxt][lo1]);
            gA0 += BK; gA1 += BK; gB0 += BK; gB1 += BK;
        }

        bf16x8 af0 = *(const bf16x8*)&As[cur][aro];
        bf16x8 af1 = *(const bf16x8*)&As[cur][aro + 16 * BK];
        bf16x8 af2 = *(const bf16x8*)&As[cur][aro + 32 * BK];
        bf16x8 af3 = *(const bf16x8*)&As[cur][aro + 48 * BK];
        bf16x8 bf0 = *(const bf16x8*)&Bs[cur][bro];
        bf16x8 bf1 = *(const bf16x8*)&Bs[cur][bro + 16 * BK];
        bf16x8 bf2 = *(const bf16x8*)&Bs[cur][bro + 32 * BK];
        bf16x8 bf3 = *(const bf16x8*)&Bs[cur][bro + 48 * BK];

        a00 = __builtin_amdgcn_mfma_f32_16x16x32_bf16(af0, bf0, a00, 0, 0, 0);
        a01 = __builtin_amdgcn_mfma_f32_16x16x32_bf16(af0, bf1, a01, 0, 0, 0);
        a02 = __builtin_amdgcn_mfma_f32_16x16x32_bf16(af0, bf2, a02, 0, 0, 0);
        a03 = __builtin_amdgcn_mfma_f32_16x16x32_bf16(af0, bf3, a03, 0, 0, 0);
        a10 = __builtin_amdgcn_mfma_f32_16x16x32_bf16(af1, bf0, a10, 0, 0, 0);
        a11 = __builtin_amdgcn_mfma_f32_16x16x32_bf16(af1, bf1, a11, 0, 0, 0);
        a12 = __builtin_amdgcn_mfma_f32_16x16x32_bf16(af1, bf2, a12, 0, 0, 0);
        a13 = __builtin_amdgcn_mfma_f32_16x16x32_bf16(af1, bf3, a13, 0, 0, 0);
        a20 = __builtin_amdgcn_mfma_f32_16x16x32_bf16(af2, bf0, a20, 0, 0, 0);
        a21 = __builtin_amdgcn_mfma_f32_16x16x32_bf16(af2, bf1, a21, 0, 0, 0);
        a22 = __builtin_amdgcn_mfma_f32_16x16x32_bf16(af2, bf2, a22, 0, 0, 0);
        a23 = __builtin_amdgcn_mfma_f32_16x16x32_bf16(af2, bf3, a23, 0, 0, 0);
        a30 = __builtin_amdgcn_mfma_f32_16x16x32_bf16(af3, bf0, a30, 0, 0, 0);
        a31 = __builtin_amdgcn_mfma_f32_16x16x32_bf16(af3, bf1, a31, 0, 0, 0);
        a32 = __builtin_amdgcn_mfma_f32_16x16x32_bf16(af3, bf2, a32, 0, 0, 0);
        a33 = __builtin_amdgcn_mfma_f32_16x16x32_bf16(af3, bf3, a33, 0, 0, 0);
    }

    const int colbase = n0 + wn * 64 + l15;

    #define EPIROW(A0, A1, A2, A3, MI)                                         \
    {                                                                          \
        _Pragma("unroll")                                                      \
        for (int r = 0; r < 4; ++r) {                                          \
            const int rloc = wm * 64 + (MI) * 16 + quad * 4 + r;               \
            const int lab = labs[rloc];                                        \
            float part = 0.f;                                                  \
            part += epi_term((A0)[r], colbase,      lab, st, m0 + rloc);       \
            part += epi_term((A1)[r], colbase + 16, lab, st, m0 + rloc);       \
            part += epi_term((A2)[r], colbase + 32, lab, st, m0 + rloc);       \
            part += epi_term((A3)[r], colbase + 48, lab, st, m0 + rloc);       \
            part += __shfl_xor(part, 1);                                       \
            part += __shfl_xor(part, 2);                                       \
            part += __shfl_xor(part, 4);                                       \
            part += __shfl_xor(part, 8);                                       \
            if (l15 == 0) atomicAdd(&rowSum[rloc], part);                      \
        }                                                                      \
    }

    EPIROW(a00, a01, a02, a03, 0)
    EPIROW(a10, a11, a12, a13, 1)
    EPIROW(a20, a21, a22, a23, 2)
    EPIROW(a30, a31, a32, a33, 3)
    #undef EPIROW

    __syncthreads();
    if (tid < BM) partial[(size_t)y * B_BATCH + m0 + tid] = rowSum[tid];
}

// ---------------- kernel 3: per-row combine + mean loss ----------------
__global__ __launch_bounds__(64) void reduce_loss(const float* __restrict__ partial,
                                                  const float* __restrict__ st,
                                                  float* __restrict__ out) {
    const int b = blockIdx.x * 64 + threadIdx.x;
    float L = 0.f;
    for (int t = 0; t < NTILES; ++t) L += partial[(size_t)t * B_BATCH + b];
    float logp = st[b] - 64.0f - logf(L);
    float lossb = fminf(-logp, NEG_LOG_EPS) * (1.0f / (float)B_BATCH);
    #pragma unroll
    for (int off = 1; off < 64; off <<= 1) lossb += __shfl_xor(lossb, off);
    if (threadIdx.x == 0) atomicAdd(out, lossb);
}

extern "C" void kernel_launch(void* const* d_in, const int* in_sizes, int n_in,
                              void* d_out, int out_size, void* d_ws, size_t ws_size,
                              hipStream_t stream) {
    const float* emb = (const float*)d_in[0];
    const float* wgt = (const float*)d_in[1];
    const int*   lab = (const int*)d_in[2];
    float* out = (float*)d_out;
    char* ws = (char*)d_ws;

    const size_t WBF_B = (size_t)C_CLASSES * D_DIM * 2;  // 102,400,000
    const size_t ABF_B = (size_t)B_BATCH * D_DIM * 2;    // 1,048,576

    unsigned short* Wbf = (unsigned short*)ws;
    unsigned short* Abf = (unsigned short*)(ws + WBF_B);
    float* st      = (float*)(ws + WBF_B + ABF_B);
    float* partial = (float*)(ws + WBF_B + ABF_B + 4096);

    hipMemsetAsync(d_out, 0, sizeof(float), stream);
    norm_embed<<<B_BATCH, 256, 0, stream>>>(emb, Abf);
    norm_weight<<<(C_CLASSES + 3) / 4, 256, 0, stream>>>(wgt, Wbf);
    gemm_cos<<<GRID_G, 256, 0, stream>>>(Abf, Wbf, lab, st, partial);
    reduce_loss<<<16, 64, 0, stream>>>(partial, st, out);
}

// Round 6
// 485.302 us; speedup vs baseline: 1.1435x; 1.1435x over previous
//
#include <hip/hip_runtime.h>
#include <hip/hip_bf16.h>
#include <math.h>
#include <stdint.h>

#define B_BATCH   1024
#define D_DIM     512
#define C_CLASSES 100000
#define BM        128
#define BN        128
#define BK        32
#define KITERS    (D_DIM / BK)                    // 16
#define MTILES    (B_BATCH / BM)                  // 8
#define NTILES    ((C_CLASSES + BN - 1) / BN)     // 782
#define NGROUPS   98                              // ceil(782/8)
#define GRID_G    (8 * 8 * NGROUPS)               // 6272 blocks (16 early-exit)
#define LOG2E     1.44269504088896340736f
#define COSM      0.87758256189037276f            // cos(0.5)
#define SINM      0.47942553860420301f            // sin(0.5)
#define NEG_LOG_EPS 69.07755278982137f            // -ln(1e-30)

typedef short bf16x8 __attribute__((ext_vector_type(8)));
typedef float f32x4  __attribute__((ext_vector_type(4)));

static __device__ __forceinline__ unsigned short f2bf(float f) {
    unsigned int u = __builtin_bit_cast(unsigned int, f);
    u += 0x7fffu + ((u >> 16) & 1u);              // round-to-nearest-even
    return (unsigned short)(u >> 16);
}

// async 16B/lane global -> LDS (LDS dest = wave-uniform base + lane*16)
static __device__ __forceinline__ void gld16(const unsigned short* g, unsigned short* l) {
    __builtin_amdgcn_global_load_lds(
        (const __attribute__((address_space(1))) unsigned int*)g,
        (__attribute__((address_space(3))) unsigned int*)l, 16, 0, 0);
}

// ---------------- kernel 1: normalize embeddings -> bf16 A [1024 x 512] ---
__global__ __launch_bounds__(256) void norm_embed(const float* __restrict__ E,
                                                  unsigned short* __restrict__ Abf) {
    const int b = blockIdx.x;
    const int t = threadIdx.x;
    float2 v = ((const float2*)(E + (size_t)b * D_DIM))[t];
    float ss = v.x * v.x + v.y * v.y;
    #pragma unroll
    for (int off = 1; off < 64; off <<= 1) ss += __shfl_xor(ss, off);
    __shared__ float ws4[4];
    if ((t & 63) == 0) ws4[t >> 6] = ss;
    __syncthreads();
    float inv = rsqrtf(ws4[0] + ws4[1] + ws4[2] + ws4[3]);
    unsigned int packed = (unsigned int)f2bf(v.x * inv) |
                          ((unsigned int)f2bf(v.y * inv) << 16);
    ((unsigned int*)Abf)[(size_t)b * (D_DIM / 2) + t] = packed;
}

// ---------------- kernel 1b: normalize weights -> bf16 [C x 512] ----------
__global__ __launch_bounds__(256) void norm_weight(const float* __restrict__ W,
                                                   unsigned short* __restrict__ Wbf) {
    const int wave = threadIdx.x >> 6;
    const int lane = threadIdx.x & 63;
    const int row = blockIdx.x * 4 + wave;
    if (row >= C_CLASSES) return;
    const float4* src = (const float4*)(W + (size_t)row * D_DIM);
    float4 v0 = src[lane];
    float4 v1 = src[lane + 64];
    float ss = v0.x*v0.x + v0.y*v0.y + v0.z*v0.z + v0.w*v0.w
             + v1.x*v1.x + v1.y*v1.y + v1.z*v1.z + v1.w*v1.w;
    #pragma unroll
    for (int off = 1; off < 64; off <<= 1) ss += __shfl_xor(ss, off);
    float inv = rsqrtf(ss);
    ushort4 o0, o1;
    o0.x = f2bf(v0.x*inv); o0.y = f2bf(v0.y*inv); o0.z = f2bf(v0.z*inv); o0.w = f2bf(v0.w*inv);
    o1.x = f2bf(v1.x*inv); o1.y = f2bf(v1.y*inv); o1.z = f2bf(v1.z*inv); o1.w = f2bf(v1.w*inv);
    ushort4* dst = (ushort4*)(Wbf + (size_t)row * D_DIM);
    dst[lane] = o0;
    dst[lane + 64] = o1;
}

// epilogue per-element: clip, ArcFace margin (identity form, no libm),
// returns exp(s - 64)
static __device__ __forceinline__ float epi_term(float accv, int col, int lab,
                                                 float* __restrict__ st, int srow) {
    float c = fminf(1.f, fmaxf(-1.f, accv));
    if (col >= C_CLASSES) return 0.f;
    float s = c * 64.0f;
    if (col == lab) {
        float sn = sqrtf(fmaxf(0.f, 1.f - c * c));
        float nm = c * COSM - sn * SINM;          // cos(theta + m)
        if (c < -COSM) nm = -1.f;                 // theta + m > pi
        s = nm * 64.0f;
        st[srow] = s;                             // unique writer across grid
    }
    return exp2f((s - 64.0f) * LOG2E);
}

// ---------------- kernel 2: bf16 GEMM + margin + partial softmax ----------
// Round-4 K-loop (single buffer, 2 barriers, 17 KB LDS -> max occupancy;
// round-5 showed 2x LDS dbuf loses more occupancy-overlap than it hides) +
// XCD-colocating 1D grid (round-5: FETCH 404 -> 54 MB): hardware XCD =
// blockIdx % 8; the 8 m-tiles sharing W n-tile y sit on 8 consecutive slots
// of ONE XCD -> W-tile is fetched once into that XCD's L2, and the exposed
// load latency at the drain barrier is L2-hit (~250 cyc) not HBM (~900 cyc).
__global__ __launch_bounds__(256) void gemm_cos(const unsigned short* __restrict__ Abf,
                                                const unsigned short* __restrict__ Wbf,
                                                const int* __restrict__ labels,
                                                float* __restrict__ st,
                                                float* __restrict__ partial) {
    __shared__ unsigned short As[BM * BK];   // 8 KiB, unpadded (global_load_lds layout)
    __shared__ unsigned short Bs[BN * BK];   // 8 KiB
    __shared__ float rowSum[BM];
    __shared__ int   labs[BM];

    const int id = blockIdx.x;
    const int x  = id & 7;          // XCD slot
    const int s  = id >> 3;         // sequence on this XCD
    const int mt = s & 7;           // m-tile
    const int y  = x + 8 * (s >> 3);// n-tile: 8 consecutive s share y per XCD
    if (y >= NTILES) return;
    const int m0 = mt * BM;
    const int n0 = y * BN;

    const int tid = threadIdx.x;
    if (tid < BM) { labs[tid] = labels[m0 + tid]; rowSum[tid] = 0.f; }

    const int lane = tid & 63;
    const int wave = tid >> 6;
    const int wm = wave & 1, wn = wave >> 1;
    const int l15 = lane & 15, quad = lane >> 4;

    // staging: wave w stages chunks (2w),(2w+1); chunk c = tile rows [16c,16c+16)
    const int rsub = lane >> 2;
    const int cg   = (lane & 3) * 8;
    const int c0 = wave * 2, c1 = wave * 2 + 1;
    const unsigned short* gA0 = Abf + (size_t)(m0 + c0 * 16 + rsub) * D_DIM + cg;
    const unsigned short* gA1 = Abf + (size_t)(m0 + c1 * 16 + rsub) * D_DIM + cg;
    const int bR0 = min(n0 + c0 * 16 + rsub, C_CLASSES - 1);
    const int bR1 = min(n0 + c1 * 16 + rsub, C_CLASSES - 1);
    const unsigned short* gB0 = Wbf + (size_t)bR0 * D_DIM + cg;
    const unsigned short* gB1 = Wbf + (size_t)bR1 * D_DIM + cg;
    unsigned short* lA0 = &As[c0 * 512];
    unsigned short* lA1 = &As[c1 * 512];
    unsigned short* lB0 = &Bs[c0 * 512];
    unsigned short* lB1 = &Bs[c1 * 512];

    const f32x4 z = (f32x4){0.f, 0.f, 0.f, 0.f};
    f32x4 a00 = z, a01 = z, a02 = z, a03 = z;
    f32x4 a10 = z, a11 = z, a12 = z, a13 = z;
    f32x4 a20 = z, a21 = z, a22 = z, a23 = z;
    f32x4 a30 = z, a31 = z, a32 = z, a33 = z;

    const int aro = (wm * 64 + l15) * BK + quad * 8;
    const int bro = (wn * 64 + l15) * BK + quad * 8;

    for (int kk = 0; kk < KITERS; ++kk) {
        __syncthreads();                     // prior frag reads done
        gld16(gA0, lA0); gld16(gA1, lA1);
        gld16(gB0, lB0); gld16(gB1, lB1);
        gA0 += BK; gA1 += BK; gB0 += BK; gB1 += BK;
        __syncthreads();                     // loads visible (L2-hit drain)

        bf16x8 af0 = *(const bf16x8*)&As[aro];
        bf16x8 af1 = *(const bf16x8*)&As[aro + 16 * BK];
        bf16x8 af2 = *(const bf16x8*)&As[aro + 32 * BK];
        bf16x8 af3 = *(const bf16x8*)&As[aro + 48 * BK];
        bf16x8 bf0 = *(const bf16x8*)&Bs[bro];
        bf16x8 bf1 = *(const bf16x8*)&Bs[bro + 16 * BK];
        bf16x8 bf2 = *(const bf16x8*)&Bs[bro + 32 * BK];
        bf16x8 bf3 = *(const bf16x8*)&Bs[bro + 48 * BK];

        a00 = __builtin_amdgcn_mfma_f32_16x16x32_bf16(af0, bf0, a00, 0, 0, 0);
        a01 = __builtin_amdgcn_mfma_f32_16x16x32_bf16(af0, bf1, a01, 0, 0, 0);
        a02 = __builtin_amdgcn_mfma_f32_16x16x32_bf16(af0, bf2, a02, 0, 0, 0);
        a03 = __builtin_amdgcn_mfma_f32_16x16x32_bf16(af0, bf3, a03, 0, 0, 0);
        a10 = __builtin_amdgcn_mfma_f32_16x16x32_bf16(af1, bf0, a10, 0, 0, 0);
        a11 = __builtin_amdgcn_mfma_f32_16x16x32_bf16(af1, bf1, a11, 0, 0, 0);
        a12 = __builtin_amdgcn_mfma_f32_16x16x32_bf16(af1, bf2, a12, 0, 0, 0);
        a13 = __builtin_amdgcn_mfma_f32_16x16x32_bf16(af1, bf3, a13, 0, 0, 0);
        a20 = __builtin_amdgcn_mfma_f32_16x16x32_bf16(af2, bf0, a20, 0, 0, 0);
        a21 = __builtin_amdgcn_mfma_f32_16x16x32_bf16(af2, bf1, a21, 0, 0, 0);
        a22 = __builtin_amdgcn_mfma_f32_16x16x32_bf16(af2, bf2, a22, 0, 0, 0);
        a23 = __builtin_amdgcn_mfma_f32_16x16x32_bf16(af2, bf3, a23, 0, 0, 0);
        a30 = __builtin_amdgcn_mfma_f32_16x16x32_bf16(af3, bf0, a30, 0, 0, 0);
        a31 = __builtin_amdgcn_mfma_f32_16x16x32_bf16(af3, bf1, a31, 0, 0, 0);
        a32 = __builtin_amdgcn_mfma_f32_16x16x32_bf16(af3, bf2, a32, 0, 0, 0);
        a33 = __builtin_amdgcn_mfma_f32_16x16x32_bf16(af3, bf3, a33, 0, 0, 0);
    }

    const int colbase = n0 + wn * 64 + l15;

    #define EPIROW(A0, A1, A2, A3, MI)                                         \
    {                                                                          \
        _Pragma("unroll")                                                      \
        for (int r = 0; r < 4; ++r) {                                          \
            const int rloc = wm * 64 + (MI) * 16 + quad * 4 + r;               \
            const int lab = labs[rloc];                                        \
            float part = 0.f;                                                  \
            part += epi_term((A0)[r], colbase,      lab, st, m0 + rloc);       \
            part += epi_term((A1)[r], colbase + 16, lab, st, m0 + rloc);       \
            part += epi_term((A2)[r], colbase + 32, lab, st, m0 + rloc);       \
            part += epi_term((A3)[r], colbase + 48, lab, st, m0 + rloc);       \
            part += __shfl_xor(part, 1);                                       \
            part += __shfl_xor(part, 2);                                       \
            part += __shfl_xor(part, 4);                                       \
            part += __shfl_xor(part, 8);                                       \
            if (l15 == 0) atomicAdd(&rowSum[rloc], part);                      \
        }                                                                      \
    }

    EPIROW(a00, a01, a02, a03, 0)
    EPIROW(a10, a11, a12, a13, 1)
    EPIROW(a20, a21, a22, a23, 2)
    EPIROW(a30, a31, a32, a33, 3)
    #undef EPIROW

    __syncthreads();
    if (tid < BM) partial[(size_t)y * B_BATCH + m0 + tid] = rowSum[tid];
}

// ---------------- kernel 3: per-row combine + mean loss ----------------
// one wave per batch row (1024 blocks): 65K threads in flight vs round-5's
// 1K -> the 782 stride-4KB loads per row are latency-hidden.
__global__ __launch_bounds__(64) void reduce_loss(const float* __restrict__ partial,
                                                  const float* __restrict__ st,
                                                  float* __restrict__ out) {
    const int b = blockIdx.x;
    const int l = threadIdx.x;
    float L = 0.f;
    for (int t = l; t < NTILES; t += 64) L += partial[(size_t)t * B_BATCH + b];
    #pragma unroll
    for (int off = 1; off < 64; off <<= 1) L += __shfl_xor(L, off);
    if (l == 0) {
        float logp = st[b] - 64.0f - logf(L);
        float lossb = fminf(-logp, NEG_LOG_EPS) * (1.0f / (float)B_BATCH);
        atomicAdd(out, lossb);
    }
}

extern "C" void kernel_launch(void* const* d_in, const int* in_sizes, int n_in,
                              void* d_out, int out_size, void* d_ws, size_t ws_size,
                              hipStream_t stream) {
    const float* emb = (const float*)d_in[0];
    const float* wgt = (const float*)d_in[1];
    const int*   lab = (const int*)d_in[2];
    float* out = (float*)d_out;
    char* ws = (char*)d_ws;

    const size_t WBF_B = (size_t)C_CLASSES * D_DIM * 2;  // 102,400,000
    const size_t ABF_B = (size_t)B_BATCH * D_DIM * 2;    // 1,048,576

    unsigned short* Wbf = (unsigned short*)ws;
    unsigned short* Abf = (unsigned short*)(ws + WBF_B);
    float* st      = (float*)(ws + WBF_B + ABF_B);
    float* partial = (float*)(ws + WBF_B + ABF_B + 4096);

    hipMemsetAsync(d_out, 0, sizeof(float), stream);
    norm_embed<<<B_BATCH, 256, 0, stream>>>(emb, Abf);
    norm_weight<<<(C_CLASSES + 3) / 4, 256, 0, stream>>>(wgt, Wbf);
    gemm_cos<<<GRID_G, 256, 0, stream>>>(Abf, Wbf, lab, st, partial);
    reduce_loss<<<B_BATCH, 64, 0, stream>>>(partial, st, out);
}